// Round 1
// baseline (1316.833 us; speedup 1.0000x reference)
//
#include <hip/hip_runtime.h>

// Problem: 64 independent 2-layer MLPs (heads), shared x[4096], per-head z[k].
//   inp_k = [x ; z_k]  (4097)
//   h = relu(W1[k] @ inp_k + b1[k])   W1: [64,1024,4097] f32  (1.074 GB -> HBM-bound)
//   f[k] = W2[k] . h + b2[k]
// Strategy: one wave per hidden row (65536 rows), float4-stream W1 at full BW.
// Row stride 4097 (odd) => per-row alignment pad; shifted x copies in LDS give
// aligned ds_read_b128/b64 for the x operand.

#define X_DIM 4096
#define Z_DIM 64
#define N_HIDDEN 1024
#define ROW_LEN 4097
#define ROWS (Z_DIM * N_HIDDEN)      // 65536
#define ROWS_PER_BLOCK 16            // 16 waves x 64 lanes = 1024 threads

__global__ void init_out_kernel(const float* __restrict__ b2, float* __restrict__ out) {
    int i = threadIdx.x;
    if (i < Z_DIM) out[i] = b2[i];
}

__global__ __launch_bounds__(1024) void mlp_heads_kernel(
    const float* __restrict__ x, const float* __restrict__ z,
    const float* __restrict__ W1, const float* __restrict__ b1,
    const float* __restrict__ W2, float* __restrict__ out)
{
    // Shifted copies of the 4097-long input vector val(c) = c<4096 ? x[c] : (c==4096 ? z_k : 0)
    // xs0[j] = val(j)   (j<4096; col 4096 handled in pad-0 epilogue)
    // xs1[j] = val(j+1) (sized 4100 so pad-3 float2 reads up to dword 4097 stay in-bounds)
    // xs2[j] = val(j+2)
    __shared__ __align__(16) float xs0[4096];
    __shared__ __align__(16) float xs1[4100];
    __shared__ __align__(16) float xs2[4096];
    __shared__ float red[ROWS_PER_BLOCK];

    const int tid = threadIdx.x;
    const int k = blockIdx.x >> 6;            // 64 blocks per head; all 16 rows same k
    const float zk = z[k];

    for (int j = tid; j < 4096; j += 1024) xs0[j] = x[j];
    for (int j = tid; j < 4100; j += 1024) {
        int c = j + 1;
        xs1[j] = (c < 4096) ? x[c] : ((c == 4096) ? zk : 0.0f);
    }
    for (int j = tid; j < 4096; j += 1024) {
        int c = j + 2;
        xs2[j] = (c < 4096) ? x[c] : ((c == 4096) ? zk : 0.0f);
    }
    __syncthreads();

    const int w = tid >> 6;                   // wave id in block
    const int l = tid & 63;                   // lane
    const int row = blockIdx.x * ROWS_PER_BLOCK + w;
    const float* Wrow = W1 + (size_t)row * ROW_LEN;
    const int pad = (4 - (row & 3)) & 3;      // (row+pad) % 4 == 0 -> 16B-aligned bulk

    float sum = 0.0f;
    if (l < pad) sum += Wrow[l] * xs0[l];     // prologue cols [0,pad)

    const float4* W4 = reinterpret_cast<const float4*>(Wrow + pad);

    if (pad == 0) {
        const float4* X4 = reinterpret_cast<const float4*>(xs0);
        #pragma unroll 4
        for (int t = l; t < 1024; t += 64) {
            float4 a = W4[t]; float4 b = X4[t];
            sum += a.x * b.x + a.y * b.y + a.z * b.z + a.w * b.w;
        }
        if (l == 0) sum += Wrow[4096] * zk;   // z element
    } else if (pad == 1) {
        // cols 1+4t .. 4+4t ; t=1023 ends exactly at col 4096 (z in xs1[4095])
        const float4* X4 = reinterpret_cast<const float4*>(xs1);
        #pragma unroll 4
        for (int t = l; t < 1024; t += 64) {
            float4 a = W4[t]; float4 b = X4[t];
            sum += a.x * b.x + a.y * b.y + a.z * b.z + a.w * b.w;
        }
    } else if (pad == 2) {
        // cols 2+4t .. 5+4t ; tail col 4097 multiplied by xs2[4095]==0 (W read 1 elem
        // into next row: row%4==2 so always within the W1 allocation)
        const float4* X4 = reinterpret_cast<const float4*>(xs2);
        #pragma unroll 4
        for (int t = l; t < 1024; t += 64) {
            float4 a = W4[t]; float4 b = X4[t];
            sum += a.x * b.x + a.y * b.y + a.z * b.z + a.w * b.w;
        }
    } else { // pad == 3
        // cols 3+4t..6+4t = xs1 dwords 2+4t..5+4t : two 8B-aligned float2 reads.
        // tail cols 4097,4098 hit xs1[4096..4097]==0 (W reads 2 elems into next row;
        // row%4==1 so row<=65533, in-allocation).
        const float2* X2 = reinterpret_cast<const float2*>(xs1);
        #pragma unroll 4
        for (int t = l; t < 1024; t += 64) {
            float4 a = W4[t];
            float2 lo = X2[1 + 2 * t];
            float2 hi = X2[2 + 2 * t];
            sum += a.x * lo.x + a.y * lo.y + a.z * hi.x + a.w * hi.y;
        }
    }

    // wave (64-lane) reduction
    #pragma unroll
    for (int off = 32; off > 0; off >>= 1) sum += __shfl_down(sum, off, 64);

    if (l == 0) {
        float h = sum + b1[row];
        red[w] = fmaxf(h, 0.0f) * W2[row];
    }
    __syncthreads();

    if (tid == 0) {
        float tot = 0.0f;
        #pragma unroll
        for (int i = 0; i < ROWS_PER_BLOCK; i++) tot += red[i];
        atomicAdd(&out[k], tot);   // 64 blocks per head -> 4096 atomics total
    }
}

extern "C" void kernel_launch(void* const* d_in, const int* in_sizes, int n_in,
                              void* d_out, int out_size, void* d_ws, size_t ws_size,
                              hipStream_t stream) {
    const float* x  = (const float*)d_in[0];
    const float* z  = (const float*)d_in[1];
    const float* W1 = (const float*)d_in[2];
    const float* b1 = (const float*)d_in[3];
    const float* W2 = (const float*)d_in[4];
    const float* b2 = (const float*)d_in[5];
    float* out = (float*)d_out;

    init_out_kernel<<<1, 64, 0, stream>>>(b2, out);
    mlp_heads_kernel<<<ROWS / ROWS_PER_BLOCK, 1024, 0, stream>>>(x, z, W1, b1, W2, out);
}